// Round 2
// baseline (183.940 us; speedup 1.0000x reference)
//
#include <hip/hip_runtime.h>

#define NV 40962
#define NF 81920
#define BSZ 8
#define CIN 32
#define COUT 64
#define BC 256   // BSZ*CIN

typedef unsigned short u16;
typedef float    f32x4 __attribute__((ext_vector_type(4)));
typedef _Float16 f16x8 __attribute__((ext_vector_type(8)));

__device__ __forceinline__ float bf2f(u16 h) {
    return __uint_as_float(((unsigned int)h) << 16);
}
__device__ __forceinline__ u16 f2bf(float f) {
    unsigned int u = __float_as_uint(f);
    unsigned int r = (u + 0x7fffu + ((u >> 16) & 1u)) >> 16;
    return (u16)r;
}

// ---------------- Kernel A: transpose input (256 x NV f32) -> xt (NV x 256 bf16)
__global__ __launch_bounds__(256) void k_transpose(const float* __restrict__ in,
                                                   u16* __restrict__ xt) {
    __shared__ float tile[32][33];   // [bc_local][v_local]
    int c0 = blockIdx.x * 32;   // v-dim tile start
    int r0 = blockIdx.y * 32;   // bc-dim tile start
    int tx = threadIdx.x & 31;
    int ty = threadIdx.x >> 5;  // 0..7
    #pragma unroll
    for (int i = 0; i < 32; i += 8) {
        int cc = c0 + tx;
        float v = 0.f;
        if (cc < NV) v = in[(size_t)(r0 + ty + i) * NV + cc];
        tile[ty + i][tx] = v;
    }
    __syncthreads();
    int t = threadIdx.x;
    #pragma unroll
    for (int e = t; e < 512; e += 256) {
        int vl = e >> 4;          // 0..31 (v_local)
        int p  = e & 15;          // channel pair
        int v  = c0 + vl;
        if (v < NV) {
            ushort2 val;
            val.x = f2bf(tile[p * 2][vl]);
            val.y = f2bf(tile[p * 2 + 1][vl]);
            *(ushort2*)&xt[(size_t)v * BC + r0 + p * 2] = val;
        }
    }
}

// ---------------- Kernel B: per-face EW/NS-folded gradient features (bf16 out)
// f is wave-uniform -> readfirstlane makes G/EW/NS scalar loads, gathers saddr-form.
__global__ __launch_bounds__(256) void k_faces(const u16* __restrict__ xt,
                                               const int* __restrict__ Gc,
                                               const float* __restrict__ Gv,
                                               const float* __restrict__ EW,
                                               const float* __restrict__ NS,
                                               u16* __restrict__ gfew,
                                               u16* __restrict__ gfns) {
    int t  = threadIdx.x;
    int fw = __builtin_amdgcn_readfirstlane(t >> 7);
    int f  = blockIdx.x * 2 + fw;         // 2 faces per block, wave-uniform
    int c2 = t & 127;                     // channel pair 0..127
    float a0ew = 0.f, a1ew = 0.f, a0ns = 0.f, a1ns = 0.f;
    #pragma unroll
    for (int d = 0; d < 3; ++d) {
        int base = 3 * (d * NF + f);
        float g0 = 0.f, g1 = 0.f;
        #pragma unroll
        for (int j = 0; j < 3; ++j) {
            int   col = Gc[base + j];          // scalar
            float val = Gv[base + j];          // scalar
            const u16* xrow = xt + (size_t)col * BC;   // scalar base
            ushort2 xv = *(const ushort2*)&xrow[c2 * 2];
            g0 += val * bf2f(xv.x);
            g1 += val * bf2f(xv.y);
        }
        float ew = EW[f * 3 + d], ns = NS[f * 3 + d];  // scalar
        a0ew += ew * g0;  a1ew += ew * g1;
        a0ns += ns * g0;  a1ns += ns * g1;
    }
    ushort2 o;
    u16* erow = gfew + (size_t)f * BC;
    u16* nrow = gfns + (size_t)f * BC;
    o.x = f2bf(a0ew); o.y = f2bf(a1ew);
    *(ushort2*)&erow[c2 * 2] = o;
    o.x = f2bf(a0ns); o.y = f2bf(a1ns);
    *(ushort2*)&nrow[c2 * 2] = o;
}

// ---------------- Kernel C: per 8-vertex tile, ALL batches+channels in one block.
// feat stored as single fp16 in LDS (17.4 KB -> 8 blocks/CU); B = coeffs hi/lo fp16.
// v is wave-uniform -> L/F indices are scalar loads, gathers saddr-form.
#define VT 8
#define FROW 136            // fp16 per feat row: 128 ck + 8 pad (272 B)
#define FBP  (16 * FROW)    // one batch-pair tile: 16 rows

__global__ __launch_bounds__(256, 8) void k_vertices(const u16* __restrict__ xt,
                                                  const int* __restrict__ Lc,
                                                  const float* __restrict__ Lv,
                                                  const int* __restrict__ Fc,
                                                  const float* __restrict__ Fv,
                                                  const u16* __restrict__ gfew,
                                                  const u16* __restrict__ gfns,
                                                  const float* __restrict__ coeffs,
                                                  float* __restrict__ out) {
    __shared__ _Float16 fh[4 * FBP];   // 17408 B
    int t = threadIdx.x;

    // ---- bijective XCD-aware swizzle (nwg = 5121, not %8==0 -> m204 form)
    const int nwg = (NV + VT - 1) / VT;
    const int q = nwg >> 3, r = nwg & 7;
    int orig = blockIdx.x;
    int xcd = orig & 7, lid = orig >> 3;
    int swz = (xcd < r ? xcd * (q + 1) : r * (q + 1) + (xcd - r) * q) + lid;
    int v0 = swz * VT;

    // ---- B fragments (coeffs 128x64 f32, L1-resident): hi/lo fp16 split
    int w  = t >> 6;          // wave id -> o-tile (w*16)
    int l  = t & 63;
    int lr = l & 15;          // o within tile / A-row
    int lq = l >> 4;          // k-octet select
    f16x8 Bh[4], Bl[4];
    #pragma unroll
    for (int ks = 0; ks < 4; ++ks) {
        #pragma unroll
        for (int e = 0; e < 8; ++e) {
            int k = ks * 32 + lq * 8 + e;
            float c = coeffs[k * 64 + w * 16 + lr];
            _Float16 h = (_Float16)c;
            Bh[ks][e] = h;
            Bl[ks][e] = (_Float16)(c - (float)h);
        }
    }

    // ---- phase 1: gather features. thread = (channel-pair p, vertex-half vh).
    // 128 threads x ushort2 = full 512B row per gather; v wave-uniform.
    int p   = t & 127;        // bc-pair: b = p>>4, c2 = p&15
    int vh  = __builtin_amdgcn_readfirstlane(t >> 7);  // 0..1, wave-uniform
    int b   = p >> 4;
    int c2  = p & 15;
    int bc0 = p * 2;          // = b*32 + c2*2
    int bp  = b >> 1;
    int rbase = (b & 1) * 8;
    #pragma unroll
    for (int vi = 0; vi < 4; ++vi) {
        int vloc = vh * 4 + vi;
        int v = v0 + vloc;    // wave-uniform
        float id0 = 0.f, id1 = 0.f, lap0 = 0.f, lap1 = 0.f;
        float ew0 = 0.f, ew1 = 0.f, ns0 = 0.f, ns1 = 0.f;
        if (v < NV) {
            const u16* vrow = xt + (size_t)v * BC;     // scalar base
            ushort2 xv = *(const ushort2*)&vrow[bc0];
            id0 = bf2f(xv.x);  id1 = bf2f(xv.y);
            #pragma unroll
            for (int j = 0; j < 7; ++j) {
                int   col = Lc[7 * v + j];             // scalar
                float val = Lv[7 * v + j];             // scalar
                const u16* xrow = xt + (size_t)col * BC;
                ushort2 lv2 = *(const ushort2*)&xrow[bc0];
                lap0 += val * bf2f(lv2.x);
                lap1 += val * bf2f(lv2.y);
            }
            #pragma unroll
            for (int j = 0; j < 6; ++j) {
                int   col = Fc[6 * v + j];             // scalar
                float val = Fv[6 * v + j];             // scalar
                const u16* erow = gfew + (size_t)col * BC;
                const u16* nrow = gfns + (size_t)col * BC;
                ushort2 e2 = *(const ushort2*)&erow[bc0];
                ushort2 n2 = *(const ushort2*)&nrow[bc0];
                ew0 += val * bf2f(e2.x);  ew1 += val * bf2f(e2.y);
                ns0 += val * bf2f(n2.x);  ns1 += val * bf2f(n2.y);
            }
        }
        float fv[8] = {id0, lap0, ew0, ns0, id1, lap1, ew1, ns1};
        f16x8 hv;
        #pragma unroll
        for (int e = 0; e < 8; ++e) hv[e] = (_Float16)fv[e];
        int idx = bp * FBP + (rbase + vloc) * FROW + c2 * 8;
        *(f16x8*)&fh[idx] = hv;
    }
    __syncthreads();

    // ---- phase 2: per wave one 16-o tile; loop 4 batch-pairs; K=128 in 4 steps.
    // A rows = (b&1)*8 + v. 2 MFMA per step (A*Bhi, A*Blo) ~= f32-coeff precision.
    #pragma unroll
    for (int bp2 = 0; bp2 < 4; ++bp2) {
        f32x4 acc = {0.f, 0.f, 0.f, 0.f};
        #pragma unroll
        for (int ks = 0; ks < 4; ++ks) {
            int aidx = bp2 * FBP + lr * FROW + ks * 32 + lq * 8;
            f16x8 A = *(const f16x8*)&fh[aidx];
            acc = __builtin_amdgcn_mfma_f32_16x16x32_f16(A, Bh[ks], acc, 0, 0, 0);
            acc = __builtin_amdgcn_mfma_f32_16x16x32_f16(A, Bl[ks], acc, 0, 0, 0);
        }
        // C layout: col = lane&15 (o), rows = lq*4 + j
        int r0 = lq * 4;
        int bb = bp2 * 2 + (r0 >> 3);
        int vbase = v0 + (r0 & 7);
        int o = w * 16 + lr;
        size_t off = ((size_t)(bb * 64 + o)) * NV + vbase;
        if (v0 + VT <= NV) {
            // off is only guaranteed 8B-aligned (NV%4==2): two float2 stores
            *(float2*)&out[off]     = make_float2(acc.x, acc.y);
            *(float2*)&out[off + 2] = make_float2(acc.z, acc.w);
        } else {
            #pragma unroll
            for (int j = 0; j < 4; ++j)
                if (vbase + j < NV) out[off + j] = acc[j];
        }
    }
}

extern "C" void kernel_launch(void* const* d_in, const int* in_sizes, int n_in,
                              void* d_out, int out_size, void* d_ws, size_t ws_size,
                              hipStream_t stream) {
    (void)in_sizes; (void)n_in; (void)out_size; (void)ws_size;
    const float* input = (const float*)d_in[0];
    const int*   Gc = (const int*)d_in[2];
    const float* Gv = (const float*)d_in[3];
    const int*   Lc = (const int*)d_in[5];
    const float* Lv = (const float*)d_in[6];
    const int*   Fc = (const int*)d_in[8];
    const float* Fv = (const float*)d_in[9];
    const float* EW = (const float*)d_in[10];
    const float* NS = (const float*)d_in[11];
    const float* coeffs = (const float*)d_in[12];
    float* out = (float*)d_out;

    u16* ws   = (u16*)d_ws;
    u16* xt   = ws;                                   // NV*256 bf16
    u16* gfew = ws + (size_t)NV * BC;                 // NF*256 bf16
    u16* gfns = gfew + (size_t)NF * BC;               // NF*256 bf16

    dim3 gA((NV + 31) / 32, BC / 32);
    k_transpose<<<gA, 256, 0, stream>>>(input, xt);

    k_faces<<<dim3(NF / 2), 256, 0, stream>>>(xt, Gc, Gv, EW, NS, gfew, gfns);

    k_vertices<<<dim3((NV + VT - 1) / VT), 256, 0, stream>>>(
        xt, Lc, Lv, Fc, Fv, gfew, gfns, coeffs, out);
}

// Round 3
// 172.857 us; speedup vs baseline: 1.0641x; 1.0641x over previous
//
#include <hip/hip_runtime.h>

#define NV 40962
#define NF 81920
#define BSZ 8
#define CIN 32
#define COUT 64
#define BC 256   // BSZ*CIN

typedef unsigned short u16;
typedef float    f32x4 __attribute__((ext_vector_type(4)));
typedef _Float16 f16x8 __attribute__((ext_vector_type(8)));

__device__ __forceinline__ float bf2f(u16 h) {
    return __uint_as_float(((unsigned int)h) << 16);
}
__device__ __forceinline__ u16 f2bf(float f) {
    unsigned int u = __float_as_uint(f);
    unsigned int r = (u + 0x7fffu + ((u >> 16) & 1u)) >> 16;
    return (u16)r;
}

// ---------------- Kernel A: transpose input (256 x NV f32) -> xt (NV x 256 bf16)
__global__ __launch_bounds__(256) void k_transpose(const float* __restrict__ in,
                                                   u16* __restrict__ xt) {
    __shared__ float tile[32][33];   // [bc_local][v_local]
    int c0 = blockIdx.x * 32;   // v-dim tile start
    int r0 = blockIdx.y * 32;   // bc-dim tile start
    int tx = threadIdx.x & 31;
    int ty = threadIdx.x >> 5;  // 0..7
    #pragma unroll
    for (int i = 0; i < 32; i += 8) {
        int cc = c0 + tx;
        float v = 0.f;
        if (cc < NV) v = in[(size_t)(r0 + ty + i) * NV + cc];
        tile[ty + i][tx] = v;
    }
    __syncthreads();
    int t = threadIdx.x;
    #pragma unroll
    for (int e = t; e < 512; e += 256) {
        int vl = e >> 4;          // 0..31 (v_local)
        int p  = e & 15;          // channel pair
        int v  = c0 + vl;
        if (v < NV) {
            ushort2 val;
            val.x = f2bf(tile[p * 2][vl]);
            val.y = f2bf(tile[p * 2 + 1][vl]);
            *(ushort2*)&xt[(size_t)v * BC + r0 + p * 2] = val;
        }
    }
}

// ---------------- Kernel B: per-face EW/NS-folded gradient features (bf16 out)
// R1 form: vector loads of Gc/Gv (same-address across lanes -> broadcast, L1-served).
__global__ __launch_bounds__(256) void k_faces(const u16* __restrict__ xt,
                                               const int* __restrict__ Gc,
                                               const float* __restrict__ Gv,
                                               const float* __restrict__ EW,
                                               const float* __restrict__ NS,
                                               u16* __restrict__ gfew,
                                               u16* __restrict__ gfns) {
    int t  = threadIdx.x;
    int f  = blockIdx.x * 2 + (t >> 7);   // 2 faces per block
    int c2 = t & 127;                     // channel pair 0..127
    float a0ew = 0.f, a1ew = 0.f, a0ns = 0.f, a1ns = 0.f;
    #pragma unroll
    for (int d = 0; d < 3; ++d) {
        int base = 3 * (d * NF + f);
        float g0 = 0.f, g1 = 0.f;
        #pragma unroll
        for (int j = 0; j < 3; ++j) {
            int   col = Gc[base + j];
            float val = Gv[base + j];
            ushort2 xv = *(const ushort2*)&xt[(size_t)col * BC + c2 * 2];
            g0 += val * bf2f(xv.x);
            g1 += val * bf2f(xv.y);
        }
        float ew = EW[f * 3 + d], ns = NS[f * 3 + d];
        a0ew += ew * g0;  a1ew += ew * g1;
        a0ns += ns * g0;  a1ns += ns * g1;
    }
    ushort2 o;
    o.x = f2bf(a0ew); o.y = f2bf(a1ew);
    *(ushort2*)&gfew[(size_t)f * BC + c2 * 2] = o;
    o.x = f2bf(a0ns); o.y = f2bf(a1ns);
    *(ushort2*)&gfns[(size_t)f * BC + c2 * 2] = o;
}

// ---------------- Kernel C: per 8-vertex tile, ALL batches+channels in one block.
// fp16 feat in LDS (17.4 KB); scalar L/F index loads (v wave-uniform);
// launch_bounds(256,6): VGPR cap 85 -> deep load batching, 6 blocks/CU.
#define VT 8
#define FROW 136            // fp16 per feat row: 128 ck + 8 pad (272 B)
#define FBP  (16 * FROW)    // one batch-pair tile: 16 rows

__global__ __launch_bounds__(256, 6) void k_vertices(const u16* __restrict__ xt,
                                                  const int* __restrict__ Lc,
                                                  const float* __restrict__ Lv,
                                                  const int* __restrict__ Fc,
                                                  const float* __restrict__ Fv,
                                                  const u16* __restrict__ gfew,
                                                  const u16* __restrict__ gfns,
                                                  const float* __restrict__ coeffs,
                                                  float* __restrict__ out) {
    __shared__ _Float16 fh[4 * FBP];   // 17408 B
    int t = threadIdx.x;

    // ---- bijective XCD-aware swizzle (nwg = 5121, not %8==0 -> m204 form)
    const int nwg = (NV + VT - 1) / VT;
    const int q = nwg >> 3, r = nwg & 7;
    int orig = blockIdx.x;
    int xcd = orig & 7, lid = orig >> 3;
    int swz = (xcd < r ? xcd * (q + 1) : r * (q + 1) + (xcd - r) * q) + lid;
    int v0 = swz * VT;

    // ---- B fragments (coeffs 128x64 f32, L1-resident): hi/lo fp16 split
    int w  = t >> 6;          // wave id -> o-tile (w*16)
    int l  = t & 63;
    int lr = l & 15;          // o within tile / A-row
    int lq = l >> 4;          // k-octet select
    f16x8 Bh[4], Bl[4];
    #pragma unroll
    for (int ks = 0; ks < 4; ++ks) {
        #pragma unroll
        for (int e = 0; e < 8; ++e) {
            int k = ks * 32 + lq * 8 + e;
            float c = coeffs[k * 64 + w * 16 + lr];
            _Float16 h = (_Float16)c;
            Bh[ks][e] = h;
            Bl[ks][e] = (_Float16)(c - (float)h);
        }
    }

    // ---- phase 1: gather features. thread = (channel-pair p, vertex-half vh).
    // Load-then-accumulate: batch all row loads into named temps so ~20 ushort2
    // gathers are in flight before the FMA chain starts (MLP >> 8-deep).
    int p   = t & 127;        // bc-pair: b = p>>4, c2 = p&15
    int vh  = __builtin_amdgcn_readfirstlane(t >> 7);  // 0..1, wave-uniform
    int b   = p >> 4;
    int c2  = p & 15;
    int bc0 = p * 2;          // = b*32 + c2*2
    int bp  = b >> 1;
    int rbase = (b & 1) * 8;
    #pragma unroll
    for (int vi = 0; vi < 4; ++vi) {
        int vloc = vh * 4 + vi;
        int v = v0 + vloc;    // wave-uniform
        float id0 = 0.f, id1 = 0.f, lap0 = 0.f, lap1 = 0.f;
        float ew0 = 0.f, ew1 = 0.f, ns0 = 0.f, ns1 = 0.f;
        if (v < NV) {
            // --- issue ALL gathers first (scalar indices -> saddr-form loads)
            ushort2 xv = *(const ushort2*)&(xt + (size_t)v * BC)[bc0];
            ushort2 lt[7];
            float   lw[7];
            #pragma unroll
            for (int j = 0; j < 7; ++j) {
                int col = Lc[7 * v + j];             // scalar
                lw[j]   = Lv[7 * v + j];             // scalar
                lt[j]   = *(const ushort2*)&(xt + (size_t)col * BC)[bc0];
            }
            ushort2 et[6], nt[6];
            float   fw6[6];
            #pragma unroll
            for (int j = 0; j < 6; ++j) {
                int col = Fc[6 * v + j];             // scalar
                fw6[j]  = Fv[6 * v + j];             // scalar
                et[j]   = *(const ushort2*)&(gfew + (size_t)col * BC)[bc0];
                nt[j]   = *(const ushort2*)&(gfns + (size_t)col * BC)[bc0];
            }
            // --- now accumulate
            id0 = bf2f(xv.x);  id1 = bf2f(xv.y);
            #pragma unroll
            for (int j = 0; j < 7; ++j) {
                lap0 += lw[j] * bf2f(lt[j].x);
                lap1 += lw[j] * bf2f(lt[j].y);
            }
            #pragma unroll
            for (int j = 0; j < 6; ++j) {
                ew0 += fw6[j] * bf2f(et[j].x);  ew1 += fw6[j] * bf2f(et[j].y);
                ns0 += fw6[j] * bf2f(nt[j].x);  ns1 += fw6[j] * bf2f(nt[j].y);
            }
        }
        float fv[8] = {id0, lap0, ew0, ns0, id1, lap1, ew1, ns1};
        f16x8 hv;
        #pragma unroll
        for (int e = 0; e < 8; ++e) hv[e] = (_Float16)fv[e];
        int idx = bp * FBP + (rbase + vloc) * FROW + c2 * 8;
        *(f16x8*)&fh[idx] = hv;
    }
    __syncthreads();

    // ---- phase 2: per wave one 16-o tile; loop 4 batch-pairs; K=128 in 4 steps.
    // A rows = (b&1)*8 + v. 2 MFMA per step (A*Bhi, A*Blo) ~= f32-coeff precision.
    #pragma unroll
    for (int bp2 = 0; bp2 < 4; ++bp2) {
        f32x4 acc = {0.f, 0.f, 0.f, 0.f};
        #pragma unroll
        for (int ks = 0; ks < 4; ++ks) {
            int aidx = bp2 * FBP + lr * FROW + ks * 32 + lq * 8;
            f16x8 A = *(const f16x8*)&fh[aidx];
            acc = __builtin_amdgcn_mfma_f32_16x16x32_f16(A, Bh[ks], acc, 0, 0, 0);
            acc = __builtin_amdgcn_mfma_f32_16x16x32_f16(A, Bl[ks], acc, 0, 0, 0);
        }
        // C layout: col = lane&15 (o), rows = lq*4 + j
        int r0 = lq * 4;
        int bb = bp2 * 2 + (r0 >> 3);
        int vbase = v0 + (r0 & 7);
        int o = w * 16 + lr;
        size_t off = ((size_t)(bb * 64 + o)) * NV + vbase;
        if (v0 + VT <= NV) {
            // off is only guaranteed 8B-aligned (NV%4==2): two float2 stores
            *(float2*)&out[off]     = make_float2(acc.x, acc.y);
            *(float2*)&out[off + 2] = make_float2(acc.z, acc.w);
        } else {
            #pragma unroll
            for (int j = 0; j < 4; ++j)
                if (vbase + j < NV) out[off + j] = acc[j];
        }
    }
}

extern "C" void kernel_launch(void* const* d_in, const int* in_sizes, int n_in,
                              void* d_out, int out_size, void* d_ws, size_t ws_size,
                              hipStream_t stream) {
    (void)in_sizes; (void)n_in; (void)out_size; (void)ws_size;
    const float* input = (const float*)d_in[0];
    const int*   Gc = (const int*)d_in[2];
    const float* Gv = (const float*)d_in[3];
    const int*   Lc = (const int*)d_in[5];
    const float* Lv = (const float*)d_in[6];
    const int*   Fc = (const int*)d_in[8];
    const float* Fv = (const float*)d_in[9];
    const float* EW = (const float*)d_in[10];
    const float* NS = (const float*)d_in[11];
    const float* coeffs = (const float*)d_in[12];
    float* out = (float*)d_out;

    u16* ws   = (u16*)d_ws;
    u16* xt   = ws;                                   // NV*256 bf16
    u16* gfew = ws + (size_t)NV * BC;                 // NF*256 bf16
    u16* gfns = gfew + (size_t)NF * BC;               // NF*256 bf16

    dim3 gA((NV + 31) / 32, BC / 32);
    k_transpose<<<gA, 256, 0, stream>>>(input, xt);

    k_faces<<<dim3(NF / 2), 256, 0, stream>>>(xt, Gc, Gv, EW, NS, gfew, gfns);

    k_vertices<<<dim3((NV + VT - 1) / VT), 256, 0, stream>>>(
        xt, Lc, Lv, Fc, Fv, gfew, gfns, coeffs, out);
}

// Round 4
// 150.956 us; speedup vs baseline: 1.2185x; 1.1451x over previous
//
#include <hip/hip_runtime.h>

#define NV 40962
#define NF 81920
#define BSZ 8
#define CIN 32
#define COUT 64
#define BC 256   // BSZ*CIN

typedef unsigned short u16;
typedef float    f32x4 __attribute__((ext_vector_type(4)));
typedef _Float16 f16x8 __attribute__((ext_vector_type(8)));
typedef unsigned short u16x4 __attribute__((ext_vector_type(4)));
typedef unsigned short u16x8 __attribute__((ext_vector_type(8)));

__device__ __forceinline__ float bf2f(u16 h) {
    return __uint_as_float(((unsigned int)h) << 16);
}
__device__ __forceinline__ u16 f2bf(float f) {
    unsigned int u = __float_as_uint(f);
    unsigned int r = (u + 0x7fffu + ((u >> 16) & 1u)) >> 16;
    return (u16)r;
}

// ---------------- Kernel A: transpose input (256 x NV f32) -> xt (NV x 256 bf16)
__global__ __launch_bounds__(256) void k_transpose(const float* __restrict__ in,
                                                   u16* __restrict__ xt) {
    __shared__ float tile[32][33];   // [bc_local][v_local]
    int c0 = blockIdx.x * 32;   // v-dim tile start
    int r0 = blockIdx.y * 32;   // bc-dim tile start
    int tx = threadIdx.x & 31;
    int ty = threadIdx.x >> 5;  // 0..7
    #pragma unroll
    for (int i = 0; i < 32; i += 8) {
        int cc = c0 + tx;
        float v = 0.f;
        if (cc < NV) v = in[(size_t)(r0 + ty + i) * NV + cc];
        tile[ty + i][tx] = v;
    }
    __syncthreads();
    int t = threadIdx.x;
    #pragma unroll
    for (int e = t; e < 512; e += 256) {
        int vl = e >> 4;          // 0..31 (v_local)
        int p  = e & 15;          // channel pair
        int v  = c0 + vl;
        if (v < NV) {
            ushort2 val;
            val.x = f2bf(tile[p * 2][vl]);
            val.y = f2bf(tile[p * 2 + 1][vl]);
            *(ushort2*)&xt[(size_t)v * BC + r0 + p * 2] = val;
        }
    }
}

// ---------------- Kernel B: wave-per-face, ushort4 gathers, interleaved output
// gfi layout: [f][C2][4] with {ew_lo, ew_hi, ns_lo, ns_hi} per channel-pair C2.
__global__ __launch_bounds__(256) void k_faces(const u16* __restrict__ xt,
                                               const int* __restrict__ Gc,
                                               const float* __restrict__ Gv,
                                               const float* __restrict__ EW,
                                               const float* __restrict__ NS,
                                               u16* __restrict__ gfi) {
    int t  = threadIdx.x;
    int f  = blockIdx.x * 4 + (t >> 6);   // wave-per-face
    int p4 = t & 63;                      // channel-quad: channels p4*4 .. +3
    int bc0 = p4 * 4;

    int   gc[9]; float gv[9];
    #pragma unroll
    for (int i = 0; i < 9; ++i) {
        int d = i / 3, j = i - d * 3;
        int base = 3 * (d * NF + f) + j;
        gc[i] = Gc[base];
        gv[i] = Gv[base];
    }
    float ewd[3], nsd[3];
    #pragma unroll
    for (int d = 0; d < 3; ++d) { ewd[d] = EW[f * 3 + d]; nsd[d] = NS[f * 3 + d]; }

    u16x4 xr[9];
    #pragma unroll
    for (int i = 0; i < 9; ++i)
        xr[i] = *(const u16x4*)&xt[(size_t)gc[i] * BC + bc0];

    float aew[4] = {0.f, 0.f, 0.f, 0.f}, ans[4] = {0.f, 0.f, 0.f, 0.f};
    #pragma unroll
    for (int d = 0; d < 3; ++d) {
        float g[4] = {0.f, 0.f, 0.f, 0.f};
        #pragma unroll
        for (int j = 0; j < 3; ++j) {
            float val = gv[d * 3 + j];
            #pragma unroll
            for (int k = 0; k < 4; ++k) g[k] += val * bf2f(xr[d * 3 + j][k]);
        }
        #pragma unroll
        for (int k = 0; k < 4; ++k) {
            aew[k] += ewd[d] * g[k];
            ans[k] += nsd[d] * g[k];
        }
    }
    u16x8 o;
    o[0] = f2bf(aew[0]); o[1] = f2bf(aew[1]); o[2] = f2bf(ans[0]); o[3] = f2bf(ans[1]);
    o[4] = f2bf(aew[2]); o[5] = f2bf(aew[3]); o[6] = f2bf(ans[2]); o[7] = f2bf(ans[3]);
    *(u16x8*)&gfi[(size_t)f * 512 + p4 * 8] = o;
}

// ---------------- Kernel C: per 8-vertex tile, all batches+channels per block.
// Thread owns 4 channels: ushort4 xt/L gathers (full row per wave-load),
// ushort8 interleaved gf gathers. 14 loads per (thread, vertex), batched.
// LDS feat fp16 with (b&3)-keyed XOR swizzle -> bank-optimal write AND read.
#define VT 8
#define FROW 136            // fp16 per feat row: 128 ck + 8 pad (272 B)
#define FBP  (16 * FROW)    // one batch-pair tile: 16 rows

__global__ __launch_bounds__(256, 4) void k_vertices(const u16* __restrict__ xt,
                                                  const int* __restrict__ Lc,
                                                  const float* __restrict__ Lv,
                                                  const int* __restrict__ Fc,
                                                  const float* __restrict__ Fv,
                                                  const u16* __restrict__ gfi,
                                                  const float* __restrict__ coeffs,
                                                  float* __restrict__ out) {
    __shared__ _Float16 fh[4 * FBP];   // 17408 B
    int t = threadIdx.x;

    // ---- bijective XCD-aware swizzle (nwg = 5121, not %8==0 -> m204 form)
    const int nwg = (NV + VT - 1) / VT;
    const int q = nwg >> 3, r = nwg & 7;
    int orig = blockIdx.x;
    int xcd = orig & 7, lid = orig >> 3;
    int swz = (xcd < r ? xcd * (q + 1) : r * (q + 1) + (xcd - r) * q) + lid;
    int v0 = swz * VT;

    // ---- phase 1: gather. thread = (bc-quad p4, wave vg); wave owns 2 vertices.
    int p4 = t & 63;          // b = p4>>3, c4 = p4&7; channels bc0..bc0+3
    int vg = t >> 6;          // wave id 0..3
    int b  = p4 >> 3;
    int c4 = p4 & 7;
    int bc0 = p4 * 4;
    int bp = b >> 1;
    int rbase = (b & 1) * 8;
    int bkey = (b & 3) << 4;  // LDS byte-XOR key

    for (int vi = 0; vi < 2; ++vi) {
        int vloc = vg * 2 + vi;
        int v = v0 + vloc;    // wave-uniform
        float id[4]  = {0.f,0.f,0.f,0.f}, lp[4] = {0.f,0.f,0.f,0.f};
        float ew[4]  = {0.f,0.f,0.f,0.f}, ns[4] = {0.f,0.f,0.f,0.f};
        if (v < NV) {
            // -- indices/weights (uniform-address vector loads, L1-broadcast)
            int   lc[7]; float lwv[7];
            #pragma unroll
            for (int j = 0; j < 7; ++j) { lc[j] = Lc[7 * v + j]; lwv[j] = Lv[7 * v + j]; }
            int   fc[6]; float fwv[6];
            #pragma unroll
            for (int j = 0; j < 6; ++j) { fc[j] = Fc[6 * v + j]; fwv[j] = Fv[6 * v + j]; }
            // -- issue all 14 gathers before consuming any
            u16x4 xv = *(const u16x4*)&xt[(size_t)v * BC + bc0];
            u16x4 lt[7];
            #pragma unroll
            for (int j = 0; j < 7; ++j)
                lt[j] = *(const u16x4*)&xt[(size_t)lc[j] * BC + bc0];
            u16x8 ft[6];
            #pragma unroll
            for (int j = 0; j < 6; ++j)
                ft[j] = *(const u16x8*)&gfi[(size_t)fc[j] * 512 + p4 * 8];
            // -- accumulate
            #pragma unroll
            for (int k = 0; k < 4; ++k) id[k] = bf2f(xv[k]);
            #pragma unroll
            for (int j = 0; j < 7; ++j)
                #pragma unroll
                for (int k = 0; k < 4; ++k) lp[k] += lwv[j] * bf2f(lt[j][k]);
            #pragma unroll
            for (int j = 0; j < 6; ++j) {
                float val = fwv[j];
                ew[0] += val * bf2f(ft[j][0]);  ew[1] += val * bf2f(ft[j][1]);
                ns[0] += val * bf2f(ft[j][2]);  ns[1] += val * bf2f(ft[j][3]);
                ew[2] += val * bf2f(ft[j][4]);  ew[3] += val * bf2f(ft[j][5]);
                ns[2] += val * bf2f(ft[j][6]);  ns[3] += val * bf2f(ft[j][7]);
            }
        }
        // -- pack 4 channels x 4 feats = 16 fp16, swizzled within the row
        int row = rbase + vloc;
        int rowsh = bp * FBP + row * FROW;             // short index of row base
        f16x8 h0, h1;
        h0[0]=(_Float16)id[0]; h0[1]=(_Float16)lp[0]; h0[2]=(_Float16)ew[0]; h0[3]=(_Float16)ns[0];
        h0[4]=(_Float16)id[1]; h0[5]=(_Float16)lp[1]; h0[6]=(_Float16)ew[1]; h0[7]=(_Float16)ns[1];
        h1[0]=(_Float16)id[2]; h1[1]=(_Float16)lp[2]; h1[2]=(_Float16)ew[2]; h1[3]=(_Float16)ns[2];
        h1[4]=(_Float16)id[3]; h1[5]=(_Float16)lp[3]; h1[6]=(_Float16)ew[3]; h1[7]=(_Float16)ns[3];
        *(f16x8*)&fh[rowsh + (((c4 * 32)      ^ bkey) >> 1)] = h0;
        *(f16x8*)&fh[rowsh + (((c4 * 32 + 16) ^ bkey) >> 1)] = h1;
    }

    // ---- B fragments (coeffs 128x64 f32, L2-hit): hi/lo fp16 split.
    // Loaded here so phase-1 register pressure stays low; overlaps barrier wait.
    int w  = vg;              // wave -> o-tile (w*16)
    int l  = t & 63;
    int lr = l & 15;          // o within tile / A-row
    int lq = l >> 4;          // k-octet select
    f16x8 Bh[4], Bl[4];
    #pragma unroll
    for (int ks = 0; ks < 4; ++ks) {
        #pragma unroll
        for (int e = 0; e < 8; ++e) {
            int k = ks * 32 + lq * 8 + e;
            float c = coeffs[k * 64 + w * 16 + lr];
            _Float16 h = (_Float16)c;
            Bh[ks][e] = h;
            Bl[ks][e] = (_Float16)(c - (float)h);
        }
    }
    __syncthreads();

    // ---- phase 2: per wave one 16-o tile; loop 4 batch-pairs; K=128 in 4 steps.
    #pragma unroll
    for (int bp2 = 0; bp2 < 4; ++bp2) {
        int akey = ((bp2 * 2 + (lr >> 3)) & 3) << 4;   // same key as writer's b&3
        f32x4 acc = {0.f, 0.f, 0.f, 0.f};
        #pragma unroll
        for (int ks = 0; ks < 4; ++ks) {
            int byteoff = (ks * 64 + lq * 16) ^ akey;
            f16x8 A = *(const f16x8*)&fh[bp2 * FBP + lr * FROW + (byteoff >> 1)];
            acc = __builtin_amdgcn_mfma_f32_16x16x32_f16(A, Bh[ks], acc, 0, 0, 0);
            acc = __builtin_amdgcn_mfma_f32_16x16x32_f16(A, Bl[ks], acc, 0, 0, 0);
        }
        // C layout: col = lane&15 (o), rows = lq*4 + j
        int r0 = lq * 4;
        int bb = bp2 * 2 + (r0 >> 3);
        int vbase = v0 + (r0 & 7);
        int o = w * 16 + lr;
        size_t off = ((size_t)(bb * 64 + o)) * NV + vbase;
        if (v0 + VT <= NV) {
            *(float2*)&out[off]     = make_float2(acc.x, acc.y);
            *(float2*)&out[off + 2] = make_float2(acc.z, acc.w);
        } else {
            #pragma unroll
            for (int j = 0; j < 4; ++j)
                if (vbase + j < NV) out[off + j] = acc[j];
        }
    }
}

extern "C" void kernel_launch(void* const* d_in, const int* in_sizes, int n_in,
                              void* d_out, int out_size, void* d_ws, size_t ws_size,
                              hipStream_t stream) {
    (void)in_sizes; (void)n_in; (void)out_size; (void)ws_size;
    const float* input = (const float*)d_in[0];
    const int*   Gc = (const int*)d_in[2];
    const float* Gv = (const float*)d_in[3];
    const int*   Lc = (const int*)d_in[5];
    const float* Lv = (const float*)d_in[6];
    const int*   Fc = (const int*)d_in[8];
    const float* Fv = (const float*)d_in[9];
    const float* EW = (const float*)d_in[10];
    const float* NS = (const float*)d_in[11];
    const float* coeffs = (const float*)d_in[12];
    float* out = (float*)d_out;

    u16* ws  = (u16*)d_ws;
    u16* xt  = ws;                       // NV*256 bf16
    u16* gfi = ws + (size_t)NV * BC;     // NF*512 bf16 (ew/ns interleaved)

    dim3 gA((NV + 31) / 32, BC / 32);
    k_transpose<<<gA, 256, 0, stream>>>(input, xt);

    k_faces<<<dim3(NF / 4), 256, 0, stream>>>(xt, Gc, Gv, EW, NS, gfi);

    k_vertices<<<dim3((NV + VT - 1) / VT), 256, 0, stream>>>(
        xt, Lc, Lv, Fc, Fv, gfi, coeffs, out);
}